// Round 8
// baseline (3249.004 us; speedup 1.0000x reference)
//
#include <hip/hip_runtime.h>

// GCN: x1 = relu(Agg(x@W1)+b1); x2 = relu(Agg(x1@W2)+b2); out = [x1,x2]@linW + linb
// Agg(h)[i] = dinv[i]^2*h[i] + sum_{e: dst=i} dinv[src]*dinv[i]*h[src]
// CSR by dst (counting sort) -> per-node wave gather-reduce. n=50000, D=128, E=800000.
// GEMM: 8x8 thread tile, 128x128 block tile. A comes straight from global
// (16 lanes share each row -> L1 broadcast); only W lives in LDS (32-k chunk,
// XOR-swizzled float4 slots: stage p=s^(s>>3), read p0=(2cg)^(cg>>2)) ->
// 0.25 LDS bytes/FLOP (was 1.25; gemm was LDS-lane-side-BW-bound at 52 TB/s).

#define D128 128

// ---------- degree count ----------
__global__ void k_count(const int* __restrict__ dst, int* __restrict__ indeg, int E) {
    int e = blockIdx.x * 256 + threadIdx.x;
    if (e < E) atomicAdd(&indeg[dst[e]], 1);
}

// ---------- scan (exclusive) over indeg -> row_ptr ; fused dinv ----------
__global__ void k_scan1(const int* __restrict__ indeg, int* __restrict__ row_ptr,
                        int* __restrict__ bsum, float* __restrict__ dinv, int n) {
    __shared__ int tmp[256];
    int i = blockIdx.x * 256 + threadIdx.x;
    int v = (i < n) ? indeg[i] : 0;
    if (i < n) dinv[i] = rsqrtf((float)(v + 1));  // +1 self loop
    tmp[threadIdx.x] = v;
    __syncthreads();
    for (int off = 1; off < 256; off <<= 1) {
        int t = (threadIdx.x >= off) ? tmp[threadIdx.x - off] : 0;
        __syncthreads();
        tmp[threadIdx.x] += t;
        __syncthreads();
    }
    if (i < n) row_ptr[i] = tmp[threadIdx.x] - v;
    if (threadIdx.x == 255) bsum[blockIdx.x] = tmp[255];
}

__global__ void k_scan2(int* __restrict__ bsum, int nb) {  // one block, nb<=256
    __shared__ int tmp[256];
    int v = (threadIdx.x < nb) ? bsum[threadIdx.x] : 0;
    tmp[threadIdx.x] = v;
    __syncthreads();
    for (int off = 1; off < 256; off <<= 1) {
        int t = (threadIdx.x >= off) ? tmp[threadIdx.x - off] : 0;
        __syncthreads();
        tmp[threadIdx.x] += t;
        __syncthreads();
    }
    if (threadIdx.x < nb) bsum[threadIdx.x] = tmp[threadIdx.x] - v;
}

__global__ void k_scan3(int* __restrict__ row_ptr, const int* __restrict__ bsum,
                        int* __restrict__ cursor, int n, int E) {
    int i = blockIdx.x * 256 + threadIdx.x;
    if (i < n) {
        int r = row_ptr[i] + bsum[blockIdx.x];
        row_ptr[i] = r;
        cursor[i] = r;
    }
    if (blockIdx.x == 0 && threadIdx.x == 0) row_ptr[n] = E;
}

// ---------- CSR fill: packed (src_bits, norm) ----------
__global__ void k_fill(const int* __restrict__ src, const int* __restrict__ dst,
                       const float* __restrict__ dinv, int* __restrict__ cursor,
                       float2* __restrict__ csr, int E) {
    int e = blockIdx.x * 256 + threadIdx.x;
    if (e >= E) return;
    int s = src[e], d = dst[e];
    int pos = atomicAdd(&cursor[d], 1);
    csr[pos] = make_float2(__int_as_float(s), dinv[s] * dinv[d]);
}

// ---------- fused aggregate + bias + relu ----------
__global__ __launch_bounds__(256) void k_agg_csr(
    const float* __restrict__ h, const int* __restrict__ row_ptr,
    const float2* __restrict__ csr, const float* __restrict__ dinv,
    const float* __restrict__ bias, float* __restrict__ o, int n)
{
    int node = blockIdx.x * 4 + (threadIdx.x >> 6);
    int lane = threadIdx.x & 63;
    if (node >= n) return;
    const float2* h2 = (const float2*)h;
    float dv = dinv[node];
    float2 hv = h2[node * 64 + lane];
    float ax = dv * dv * hv.x, ay = dv * dv * hv.y;
    int j = row_ptr[node], end = row_ptr[node + 1];
    for (; j + 7 < end; j += 8) {
        float2 c0 = csr[j+0], c1 = csr[j+1], c2 = csr[j+2], c3 = csr[j+3];
        float2 c4 = csr[j+4], c5 = csr[j+5], c6 = csr[j+6], c7 = csr[j+7];
        float2 v0 = h2[__float_as_int(c0.x) * 64 + lane];
        float2 v1 = h2[__float_as_int(c1.x) * 64 + lane];
        float2 v2 = h2[__float_as_int(c2.x) * 64 + lane];
        float2 v3 = h2[__float_as_int(c3.x) * 64 + lane];
        float2 v4 = h2[__float_as_int(c4.x) * 64 + lane];
        float2 v5 = h2[__float_as_int(c5.x) * 64 + lane];
        float2 v6 = h2[__float_as_int(c6.x) * 64 + lane];
        float2 v7 = h2[__float_as_int(c7.x) * 64 + lane];
        ax += c0.y*v0.x + c1.y*v1.x + c2.y*v2.x + c3.y*v3.x
            + c4.y*v4.x + c5.y*v5.x + c6.y*v6.x + c7.y*v7.x;
        ay += c0.y*v0.y + c1.y*v1.y + c2.y*v2.y + c3.y*v3.y
            + c4.y*v4.y + c5.y*v5.y + c6.y*v6.y + c7.y*v7.y;
    }
    for (; j + 3 < end; j += 4) {
        float2 c0 = csr[j+0], c1 = csr[j+1], c2 = csr[j+2], c3 = csr[j+3];
        float2 v0 = h2[__float_as_int(c0.x) * 64 + lane];
        float2 v1 = h2[__float_as_int(c1.x) * 64 + lane];
        float2 v2 = h2[__float_as_int(c2.x) * 64 + lane];
        float2 v3 = h2[__float_as_int(c3.x) * 64 + lane];
        ax += c0.y*v0.x + c1.y*v1.x + c2.y*v2.x + c3.y*v3.x;
        ay += c0.y*v0.y + c1.y*v1.y + c2.y*v2.y + c3.y*v3.y;
    }
    for (; j < end; ++j) {
        float2 c = csr[j];
        float2 v = h2[__float_as_int(c.x) * 64 + lane];
        ax += c.y * v.x;
        ay += c.y * v.y;
    }
    float2 bv = ((const float2*)bias)[lane];
    float2 ov = {fmaxf(ax + bv.x, 0.f), fmaxf(ay + bv.y, 0.f)};
    ((float2*)o)[node * 64 + lane] = ov;
}

// ---------- GEMM helpers ----------
__device__ __forceinline__ void fma4(float4& d, float a, const float4& v) {
    d.x += a * v.x; d.y += a * v.y; d.z += a * v.z; d.w += a * v.w;
}

// Stage 32 k-rows x 128 cols of W into Wc, XOR-swizzled float4 slots.
__device__ __forceinline__ void stage_W32(const float* __restrict__ Wsrc, float* Wc, int tid) {
    const float4* W4 = (const float4*)Wsrc;
#pragma unroll
    for (int it = 0; it < 4; ++it) {
        int f = it * 256 + tid;       // float4 idx in 32x32 slot grid
        int r = f >> 5, s = f & 31;
        int p = s ^ (s >> 3);
        *(float4*)&Wc[r * D128 + p * 4] = W4[f];
    }
}

// ---------- dense GEMM: C[128 x 128] = A@W, K=128; thread = 8 rows x 8 cols ----------
__global__ __launch_bounds__(256, 3) void k_gemm(
    const float* __restrict__ A, const float* __restrict__ W,
    float* __restrict__ C, int n)
{
    __shared__ float Wc[32 * D128];   // 16 KB
    int tid = threadIdx.x;
    int cg = tid & 15;                // cols cg*8 .. cg*8+7
    int rg = tid >> 4;                // rows rg*8 .. rg*8+7
    int p0 = (2 * cg) ^ (cg >> 2);
    int rbase = blockIdx.x * 128 + rg * 8;

    const float4* A4 = (const float4*)A;
    float4 acc[8][2];
#pragma unroll
    for (int j = 0; j < 8; ++j) { acc[j][0] = make_float4(0,0,0,0); acc[j][1] = make_float4(0,0,0,0); }

    for (int kb = 0; kb < 4; ++kb) {
        if (kb) __syncthreads();
        stage_W32(W + kb * 32 * D128, Wc, tid);
        __syncthreads();

#pragma unroll
        for (int k4 = 0; k4 < 8; ++k4) {
            float4 ar[8];
#pragma unroll
            for (int j = 0; j < 8; ++j) {
                int row = rbase + j;
                ar[j] = (row < n) ? A4[(size_t)row * 32 + kb * 8 + k4]
                                  : make_float4(0,0,0,0);
            }
#pragma unroll
            for (int kk = 0; kk < 4; ++kk) {
                int k = k4 * 4 + kk;
                float4 w0 = *(const float4*)&Wc[k * D128 + p0 * 4];
                float4 w1 = *(const float4*)&Wc[k * D128 + (p0 ^ 1) * 4];
#pragma unroll
                for (int j = 0; j < 8; ++j) {
                    float a = (kk == 0) ? ar[j].x : (kk == 1) ? ar[j].y : (kk == 2) ? ar[j].z : ar[j].w;
                    fma4(acc[j][0], a, w0);
                    fma4(acc[j][1], a, w1);
                }
            }
        }
    }

#pragma unroll
    for (int j = 0; j < 8; ++j) {
        int row = rbase + j;
        if (row < n) {
            float4* Cp = (float4*)&C[(size_t)row * D128 + cg * 8];
            Cp[0] = acc[j][0];
            Cp[1] = acc[j][1];
        }
    }
}

// ---------- final: out = [x1,x2] @ linW + linb  (K=256 in 8 chunks of 32) ----------
__global__ __launch_bounds__(256, 3) void k_gemm_cat(
    const float* __restrict__ A0, const float* __restrict__ A1,
    const float* __restrict__ W, const float* __restrict__ bias,
    float* __restrict__ C, int n)
{
    __shared__ float Wc[32 * D128];   // 16 KB
    int tid = threadIdx.x;
    int cg = tid & 15;
    int rg = tid >> 4;
    int p0 = (2 * cg) ^ (cg >> 2);
    int rbase = blockIdx.x * 128 + rg * 8;

    float4 acc[8][2];
#pragma unroll
    for (int j = 0; j < 8; ++j) { acc[j][0] = make_float4(0,0,0,0); acc[j][1] = make_float4(0,0,0,0); }

    for (int kb = 0; kb < 8; ++kb) {
        if (kb) __syncthreads();
        stage_W32(W + kb * 32 * D128, Wc, tid);
        __syncthreads();

        const float4* A4 = (const float4*)((kb < 4) ? A0 : A1);
        int cb = (kb & 3) * 8;
#pragma unroll
        for (int k4 = 0; k4 < 8; ++k4) {
            float4 ar[8];
#pragma unroll
            for (int j = 0; j < 8; ++j) {
                int row = rbase + j;
                ar[j] = (row < n) ? A4[(size_t)row * 32 + cb + k4]
                                  : make_float4(0,0,0,0);
            }
#pragma unroll
            for (int kk = 0; kk < 4; ++kk) {
                int k = k4 * 4 + kk;
                float4 w0 = *(const float4*)&Wc[k * D128 + p0 * 4];
                float4 w1 = *(const float4*)&Wc[k * D128 + (p0 ^ 1) * 4];
#pragma unroll
                for (int j = 0; j < 8; ++j) {
                    float a = (kk == 0) ? ar[j].x : (kk == 1) ? ar[j].y : (kk == 2) ? ar[j].z : ar[j].w;
                    fma4(acc[j][0], a, w0);
                    fma4(acc[j][1], a, w1);
                }
            }
        }
    }

    float4 bv0 = ((const float4*)bias)[cg * 2];
    float4 bv1 = ((const float4*)bias)[cg * 2 + 1];
#pragma unroll
    for (int j = 0; j < 8; ++j) {
        int row = rbase + j;
        if (row < n) {
            float4* Cp = (float4*)&C[(size_t)row * D128 + cg * 8];
            float4 v0 = acc[j][0], v1 = acc[j][1];
            v0.x += bv0.x; v0.y += bv0.y; v0.z += bv0.z; v0.w += bv0.w;
            v1.x += bv1.x; v1.y += bv1.y; v1.z += bv1.z; v1.w += bv1.w;
            Cp[0] = v0;
            Cp[1] = v1;
        }
    }
}

extern "C" void kernel_launch(void* const* d_in, const int* in_sizes, int n_in,
                              void* d_out, int out_size, void* d_ws, size_t ws_size,
                              hipStream_t stream) {
    const float* x    = (const float*)d_in[0];
    const int*   ei   = (const int*)d_in[1];
    const float* W1   = (const float*)d_in[2];
    const float* b1   = (const float*)d_in[3];
    const float* W2   = (const float*)d_in[4];
    const float* b2   = (const float*)d_in[5];
    const float* linW = (const float*)d_in[6];
    const float* linb = (const float*)d_in[7];

    int n = in_sizes[0] / D128;
    int E = in_sizes[1] / 2;
    const int* src = ei;
    const int* dst = ei + E;

    float* out = (float*)d_out;
    float* ws  = (float*)d_ws;

    // ws layout (floats): csr[2E] | indeg[n] | dinv[n] | row_ptr[n+1] | bsum[256]
    //                     | cursor[n] | (align) | x1[n*128] | x2[n*128]
    size_t o = 0;
    float2* csr   = (float2*)(ws + o);  o += 2 * (size_t)E;
    int*   indeg  = (int*)(ws + o);     o += n;
    float* dinv   = ws + o;             o += n;
    int*   row_ptr= (int*)(ws + o);     o += n + 1;
    int*   bsum   = (int*)(ws + o);     o += 256;
    int*   cursor = (int*)(ws + o);     o += n;
    o = (o + 3) & ~(size_t)3;
    float* x1     = ws + o;             o += (size_t)n * D128;
    float* x2     = ws + o;
    float* h      = out;  // reuse output buffer as GEMM scratch

    int gn = (n + 255) / 256;
    int gE = (E + 255) / 256;
    int gemmBlocks = (n + 127) / 128;
    int aggBlocks  = (n + 3) / 4;

    // CSR build
    (void)hipMemsetAsync(indeg, 0, (size_t)n * sizeof(int), stream);
    k_count<<<gE, 256, 0, stream>>>(dst, indeg, E);
    k_scan1<<<gn, 256, 0, stream>>>(indeg, row_ptr, bsum, dinv, n);
    k_scan2<<<1, 256, 0, stream>>>(bsum, gn);
    k_scan3<<<gn, 256, 0, stream>>>(row_ptr, bsum, cursor, n, E);
    k_fill<<<gE, 256, 0, stream>>>(src, dst, dinv, cursor, csr, E);

    // layer 1
    k_gemm<<<gemmBlocks, 256, 0, stream>>>(x, W1, h, n);
    k_agg_csr<<<aggBlocks, 256, 0, stream>>>(h, row_ptr, csr, dinv, b1, x1, n);

    // layer 2
    k_gemm<<<gemmBlocks, 256, 0, stream>>>(x1, W2, h, n);
    k_agg_csr<<<aggBlocks, 256, 0, stream>>>(h, row_ptr, csr, dinv, b2, x2, n);

    // final
    k_gemm_cat<<<gemmBlocks, 256, 0, stream>>>(x1, x2, linW, linb, out, n);
}

// Round 9
// 358.012 us; speedup vs baseline: 9.0751x; 9.0751x over previous
//
#include <hip/hip_runtime.h>

// GCN: x1 = relu(Agg(x@W1)+b1); x2 = relu(Agg(x1@W2)+b2); out = [x1,x2]@linW + linb
// Agg(h)[i] = dinv[i]^2*h[i] + sum_{e: dst=i} dinv[src]*dinv[i]*h[src]
// CSR by dst (counting sort) -> per-node wave gather-reduce. n=50000, D=128, E=800000.
// GEMM = R2-kernel structure (proven): block 16x128, thread 4 rows x 2 cols,
// full W in LDS, float2 w-reads (bank-minimal). Fix: As row stride 132
// (128 % 32banks == 0 made the 4 rq-groups collide 4-way on every a-read).

#define D128 128
#define AS_STRIDE 132

// ---------- degree count ----------
__global__ void k_count(const int* __restrict__ dst, int* __restrict__ indeg, int E) {
    int e = blockIdx.x * 256 + threadIdx.x;
    if (e < E) atomicAdd(&indeg[dst[e]], 1);
}

// ---------- scan (exclusive) over indeg -> row_ptr ; fused dinv ----------
__global__ void k_scan1(const int* __restrict__ indeg, int* __restrict__ row_ptr,
                        int* __restrict__ bsum, float* __restrict__ dinv, int n) {
    __shared__ int tmp[256];
    int i = blockIdx.x * 256 + threadIdx.x;
    int v = (i < n) ? indeg[i] : 0;
    if (i < n) dinv[i] = rsqrtf((float)(v + 1));  // +1 self loop
    tmp[threadIdx.x] = v;
    __syncthreads();
    for (int off = 1; off < 256; off <<= 1) {
        int t = (threadIdx.x >= off) ? tmp[threadIdx.x - off] : 0;
        __syncthreads();
        tmp[threadIdx.x] += t;
        __syncthreads();
    }
    if (i < n) row_ptr[i] = tmp[threadIdx.x] - v;
    if (threadIdx.x == 255) bsum[blockIdx.x] = tmp[255];
}

__global__ void k_scan2(int* __restrict__ bsum, int nb) {  // one block, nb<=256
    __shared__ int tmp[256];
    int v = (threadIdx.x < nb) ? bsum[threadIdx.x] : 0;
    tmp[threadIdx.x] = v;
    __syncthreads();
    for (int off = 1; off < 256; off <<= 1) {
        int t = (threadIdx.x >= off) ? tmp[threadIdx.x - off] : 0;
        __syncthreads();
        tmp[threadIdx.x] += t;
        __syncthreads();
    }
    if (threadIdx.x < nb) bsum[threadIdx.x] = tmp[threadIdx.x] - v;
}

__global__ void k_scan3(int* __restrict__ row_ptr, const int* __restrict__ bsum,
                        int* __restrict__ cursor, int n, int E) {
    int i = blockIdx.x * 256 + threadIdx.x;
    if (i < n) {
        int r = row_ptr[i] + bsum[blockIdx.x];
        row_ptr[i] = r;
        cursor[i] = r;
    }
    if (blockIdx.x == 0 && threadIdx.x == 0) row_ptr[n] = E;
}

// ---------- CSR fill: packed (src_bits, norm) ----------
__global__ void k_fill(const int* __restrict__ src, const int* __restrict__ dst,
                       const float* __restrict__ dinv, int* __restrict__ cursor,
                       float2* __restrict__ csr, int E) {
    int e = blockIdx.x * 256 + threadIdx.x;
    if (e >= E) return;
    int s = src[e], d = dst[e];
    int pos = atomicAdd(&cursor[d], 1);
    csr[pos] = make_float2(__int_as_float(s), dinv[s] * dinv[d]);
}

// ---------- fused aggregate + bias + relu ----------
// 1 wave per node, float2 per lane; 8 gathers in flight. (proven, 60.5 us)
__global__ __launch_bounds__(256) void k_agg_csr(
    const float* __restrict__ h, const int* __restrict__ row_ptr,
    const float2* __restrict__ csr, const float* __restrict__ dinv,
    const float* __restrict__ bias, float* __restrict__ o, int n)
{
    int node = blockIdx.x * 4 + (threadIdx.x >> 6);
    int lane = threadIdx.x & 63;
    if (node >= n) return;
    const float2* h2 = (const float2*)h;
    float dv = dinv[node];
    float2 hv = h2[node * 64 + lane];
    float ax = dv * dv * hv.x, ay = dv * dv * hv.y;
    int j = row_ptr[node], end = row_ptr[node + 1];
    for (; j + 7 < end; j += 8) {
        float2 c0 = csr[j+0], c1 = csr[j+1], c2 = csr[j+2], c3 = csr[j+3];
        float2 c4 = csr[j+4], c5 = csr[j+5], c6 = csr[j+6], c7 = csr[j+7];
        float2 v0 = h2[__float_as_int(c0.x) * 64 + lane];
        float2 v1 = h2[__float_as_int(c1.x) * 64 + lane];
        float2 v2 = h2[__float_as_int(c2.x) * 64 + lane];
        float2 v3 = h2[__float_as_int(c3.x) * 64 + lane];
        float2 v4 = h2[__float_as_int(c4.x) * 64 + lane];
        float2 v5 = h2[__float_as_int(c5.x) * 64 + lane];
        float2 v6 = h2[__float_as_int(c6.x) * 64 + lane];
        float2 v7 = h2[__float_as_int(c7.x) * 64 + lane];
        ax += c0.y*v0.x + c1.y*v1.x + c2.y*v2.x + c3.y*v3.x
            + c4.y*v4.x + c5.y*v5.x + c6.y*v6.x + c7.y*v7.x;
        ay += c0.y*v0.y + c1.y*v1.y + c2.y*v2.y + c3.y*v3.y
            + c4.y*v4.y + c5.y*v5.y + c6.y*v6.y + c7.y*v7.y;
    }
    for (; j + 3 < end; j += 4) {
        float2 c0 = csr[j+0], c1 = csr[j+1], c2 = csr[j+2], c3 = csr[j+3];
        float2 v0 = h2[__float_as_int(c0.x) * 64 + lane];
        float2 v1 = h2[__float_as_int(c1.x) * 64 + lane];
        float2 v2 = h2[__float_as_int(c2.x) * 64 + lane];
        float2 v3 = h2[__float_as_int(c3.x) * 64 + lane];
        ax += c0.y*v0.x + c1.y*v1.x + c2.y*v2.x + c3.y*v3.x;
        ay += c0.y*v0.y + c1.y*v1.y + c2.y*v2.y + c3.y*v3.y;
    }
    for (; j < end; ++j) {
        float2 c = csr[j];
        float2 v = h2[__float_as_int(c.x) * 64 + lane];
        ax += c.y * v.x;
        ay += c.y * v.y;
    }
    float2 bv = ((const float2*)bias)[lane];
    float2 ov = {fmaxf(ax + bv.x, 0.f), fmaxf(ay + bv.y, 0.f)};
    ((float2*)o)[node * 64 + lane] = ov;
}

// ---------- GEMM tile helpers (R2 structure) ----------
// stage full 128x128 W (linear; b128 writes are bank-uniform)
__device__ __forceinline__ void stage_Wfull(const float* __restrict__ Wsrc,
                                            float* __restrict__ Ws, int tid) {
    const float4* W4 = (const float4*)Wsrc;
    float4* Ws4 = (float4*)Ws;
#pragma unroll
    for (int it = 0; it < 16; ++it)
        Ws4[it * 256 + tid] = W4[it * 256 + tid];
}

// stage 16x128 A tile into padded-stride LDS
__device__ __forceinline__ void stage_A16(const float* __restrict__ Asrc,
                                          float* __restrict__ As, int tid) {
    const float4* A4 = (const float4*)Asrc;
#pragma unroll
    for (int it = 0; it < 2; ++it) {
        int f = it * 256 + tid;      // float4 idx in 16x32 grid
        int r = f >> 5, c4 = f & 31;
        *(float4*)&As[r * AS_STRIDE + c4 * 4] = A4[f];
    }
}

// inner accumulate over K=128 for 4 rows x 2 cols per thread
__device__ __forceinline__ void gemm_inner(const float* __restrict__ Ws,
                                           const float* __restrict__ As,
                                           int cp, int rq, float2 acc[4]) {
#pragma unroll 8
    for (int k = 0; k < 128; ++k) {
        float2 w = *(const float2*)&Ws[k * D128 + cp * 2];
#pragma unroll
        for (int r = 0; r < 4; ++r) {
            float a = As[(rq * 4 + r) * AS_STRIDE + k];
            acc[r].x += a * w.x;
            acc[r].y += a * w.y;
        }
    }
}

// ---------- dense GEMM: C[16 x 128] = A@W (K=128); n % 16 == 0 ----------
__global__ __launch_bounds__(256) void k_gemm128(
    const float* __restrict__ A, const float* __restrict__ W,
    float* __restrict__ C)
{
    __shared__ float Ws[128 * D128];       // 64 KB
    __shared__ float As[16 * AS_STRIDE];   // 8.25 KB
    int tid = threadIdx.x;
    long long row0 = (long long)blockIdx.x * 16;

    stage_Wfull(W, Ws, tid);
    stage_A16(A + row0 * D128, As, tid);
    __syncthreads();

    int cp = tid & 63;   // cols 2cp, 2cp+1
    int rq = tid >> 6;   // rows rq*4 .. rq*4+3
    float2 acc[4] = {{0.f,0.f},{0.f,0.f},{0.f,0.f},{0.f,0.f}};
    gemm_inner(Ws, As, cp, rq, acc);

#pragma unroll
    for (int r = 0; r < 4; ++r) {
        long long row = row0 + rq * 4 + r;
        *(float2*)&C[row * D128 + cp * 2] = acc[r];
    }
}

// ---------- final fused: out = [x1,x2] @ linW + linb (two K=128 halves) ----------
__global__ __launch_bounds__(256) void k_gemm_cat128(
    const float* __restrict__ A0, const float* __restrict__ A1,
    const float* __restrict__ W, const float* __restrict__ bias,
    float* __restrict__ C)
{
    __shared__ float Ws[128 * D128];       // 64 KB
    __shared__ float As[16 * AS_STRIDE];   // 8.25 KB
    int tid = threadIdx.x;
    long long row0 = (long long)blockIdx.x * 16;

    int cp = tid & 63;
    int rq = tid >> 6;
    float2 acc[4] = {{0.f,0.f},{0.f,0.f},{0.f,0.f},{0.f,0.f}};

    // half 0: x1 @ linW[0:128]
    stage_Wfull(W, Ws, tid);
    stage_A16(A0 + row0 * D128, As, tid);
    __syncthreads();
    gemm_inner(Ws, As, cp, rq, acc);
    __syncthreads();   // done reading before restage

    // half 1: x2 @ linW[128:256]
    stage_Wfull(W + 128 * D128, Ws, tid);
    stage_A16(A1 + row0 * D128, As, tid);
    __syncthreads();
    gemm_inner(Ws, As, cp, rq, acc);

    float2 bv = *(const float2*)&bias[cp * 2];
#pragma unroll
    for (int r = 0; r < 4; ++r) {
        long long row = row0 + rq * 4 + r;
        float2 v = acc[r];
        v.x += bv.x; v.y += bv.y;
        *(float2*)&C[row * D128 + cp * 2] = v;
    }
}

extern "C" void kernel_launch(void* const* d_in, const int* in_sizes, int n_in,
                              void* d_out, int out_size, void* d_ws, size_t ws_size,
                              hipStream_t stream) {
    const float* x    = (const float*)d_in[0];
    const int*   ei   = (const int*)d_in[1];
    const float* W1   = (const float*)d_in[2];
    const float* b1   = (const float*)d_in[3];
    const float* W2   = (const float*)d_in[4];
    const float* b2   = (const float*)d_in[5];
    const float* linW = (const float*)d_in[6];
    const float* linb = (const float*)d_in[7];

    int n = in_sizes[0] / D128;
    int E = in_sizes[1] / 2;
    const int* src = ei;
    const int* dst = ei + E;

    float* out = (float*)d_out;
    float* ws  = (float*)d_ws;

    // ws layout (floats): csr[2E] | indeg[n] | dinv[n] | row_ptr[n+1] | bsum[256]
    //                     | cursor[n] | (align) | x1[n*128] | x2[n*128]
    size_t o = 0;
    float2* csr   = (float2*)(ws + o);  o += 2 * (size_t)E;
    int*   indeg  = (int*)(ws + o);     o += n;
    float* dinv   = ws + o;             o += n;
    int*   row_ptr= (int*)(ws + o);     o += n + 1;
    int*   bsum   = (int*)(ws + o);     o += 256;
    int*   cursor = (int*)(ws + o);     o += n;
    o = (o + 3) & ~(size_t)3;
    float* x1     = ws + o;             o += (size_t)n * D128;
    float* x2     = ws + o;
    float* h      = out;  // reuse output buffer as GEMM scratch

    int gn = (n + 255) / 256;
    int gE = (E + 255) / 256;
    int gemmBlocks = n / 16;            // n % 16 == 0 (50000 = 16*3125)
    int aggBlocks  = (n + 3) / 4;

    // CSR build
    (void)hipMemsetAsync(indeg, 0, (size_t)n * sizeof(int), stream);
    k_count<<<gE, 256, 0, stream>>>(dst, indeg, E);
    k_scan1<<<gn, 256, 0, stream>>>(indeg, row_ptr, bsum, dinv, n);
    k_scan2<<<1, 256, 0, stream>>>(bsum, gn);
    k_scan3<<<gn, 256, 0, stream>>>(row_ptr, bsum, cursor, n, E);
    k_fill<<<gE, 256, 0, stream>>>(src, dst, dinv, cursor, csr, E);

    // layer 1
    k_gemm128<<<gemmBlocks, 256, 0, stream>>>(x, W1, h);
    k_agg_csr<<<aggBlocks, 256, 0, stream>>>(h, row_ptr, csr, dinv, b1, x1, n);

    // layer 2
    k_gemm128<<<gemmBlocks, 256, 0, stream>>>(x1, W2, h);
    k_agg_csr<<<aggBlocks, 256, 0, stream>>>(h, row_ptr, csr, dinv, b2, x2, n);

    // final
    k_gemm_cat128<<<gemmBlocks, 256, 0, stream>>>(x1, x2, linW, linb, out);
}

// Round 10
// 301.024 us; speedup vs baseline: 10.7932x; 1.1893x over previous
//
#include <hip/hip_runtime.h>

// GCN: x1 = relu(Agg(x@W1)+b1); x2 = relu(Agg(x1@W2)+b2); out = [x1,x2]@linW + linb
// Agg via CSR (counting sort) + per-node wave gather-reduce (proven, ~60.5us).
// GEMMs via MFMA bf16x3 fp32-emulation: A,W split hi+lo bf16; acc fp32;
// hi*hi + lo*hi + hi*lo (residual ~K*2^-17 ~ 4e-3 << 1.5e-2 threshold).
// Block: 64 rows x 128 cols, 4 waves; wave owns 32 cols, W-frags in regs;
// A staged to LDS in fragment order (contiguous b128 frag reads).
// mfma_f32_16x16x32_bf16 layouts: A m=lane&15,k=(lane>>4)*8+j; B n=lane&15,
// k=(lane>>4)*8+j; D col=lane&15,row=(lane>>4)*4+reg [m89-verified].

#define D128 128

typedef __attribute__((ext_vector_type(8))) short bf16x8;
typedef __attribute__((ext_vector_type(4))) float f32x4;

__device__ __forceinline__ unsigned short f2bf_bits(float v) {
    unsigned int u = __float_as_uint(v);
    unsigned int r = u + 0x7FFFu + ((u >> 16) & 1u);   // RNE
    return (unsigned short)(r >> 16);
}
__device__ __forceinline__ float bf2f(unsigned short h) {
    return __uint_as_float(((unsigned int)h) << 16);
}

// ---------- degree count ----------
__global__ void k_count(const int* __restrict__ dst, int* __restrict__ indeg, int E) {
    int e = blockIdx.x * 256 + threadIdx.x;
    if (e < E) atomicAdd(&indeg[dst[e]], 1);
}

// ---------- scan (exclusive) over indeg -> row_ptr ; fused dinv ----------
__global__ void k_scan1(const int* __restrict__ indeg, int* __restrict__ row_ptr,
                        int* __restrict__ bsum, float* __restrict__ dinv, int n) {
    __shared__ int tmp[256];
    int i = blockIdx.x * 256 + threadIdx.x;
    int v = (i < n) ? indeg[i] : 0;
    if (i < n) dinv[i] = rsqrtf((float)(v + 1));  // +1 self loop
    tmp[threadIdx.x] = v;
    __syncthreads();
    for (int off = 1; off < 256; off <<= 1) {
        int t = (threadIdx.x >= off) ? tmp[threadIdx.x - off] : 0;
        __syncthreads();
        tmp[threadIdx.x] += t;
        __syncthreads();
    }
    if (i < n) row_ptr[i] = tmp[threadIdx.x] - v;
    if (threadIdx.x == 255) bsum[blockIdx.x] = tmp[255];
}

__global__ void k_scan2(int* __restrict__ bsum, int nb) {  // one block, nb<=256
    __shared__ int tmp[256];
    int v = (threadIdx.x < nb) ? bsum[threadIdx.x] : 0;
    tmp[threadIdx.x] = v;
    __syncthreads();
    for (int off = 1; off < 256; off <<= 1) {
        int t = (threadIdx.x >= off) ? tmp[threadIdx.x - off] : 0;
        __syncthreads();
        tmp[threadIdx.x] += t;
        __syncthreads();
    }
    if (threadIdx.x < nb) bsum[threadIdx.x] = tmp[threadIdx.x] - v;
}

__global__ void k_scan3(int* __restrict__ row_ptr, const int* __restrict__ bsum,
                        int* __restrict__ cursor, int n, int E) {
    int i = blockIdx.x * 256 + threadIdx.x;
    if (i < n) {
        int r = row_ptr[i] + bsum[blockIdx.x];
        row_ptr[i] = r;
        cursor[i] = r;
    }
    if (blockIdx.x == 0 && threadIdx.x == 0) row_ptr[n] = E;
}

// ---------- CSR fill: packed (src_bits, norm) ----------
__global__ void k_fill(const int* __restrict__ src, const int* __restrict__ dst,
                       const float* __restrict__ dinv, int* __restrict__ cursor,
                       float2* __restrict__ csr, int E) {
    int e = blockIdx.x * 256 + threadIdx.x;
    if (e >= E) return;
    int s = src[e], d = dst[e];
    int pos = atomicAdd(&cursor[d], 1);
    csr[pos] = make_float2(__int_as_float(s), dinv[s] * dinv[d]);
}

// ---------- fused aggregate + bias + relu (proven) ----------
__global__ __launch_bounds__(256) void k_agg_csr(
    const float* __restrict__ h, const int* __restrict__ row_ptr,
    const float2* __restrict__ csr, const float* __restrict__ dinv,
    const float* __restrict__ bias, float* __restrict__ o, int n)
{
    int node = blockIdx.x * 4 + (threadIdx.x >> 6);
    int lane = threadIdx.x & 63;
    if (node >= n) return;
    const float2* h2 = (const float2*)h;
    float dv = dinv[node];
    float2 hv = h2[node * 64 + lane];
    float ax = dv * dv * hv.x, ay = dv * dv * hv.y;
    int j = row_ptr[node], end = row_ptr[node + 1];
    for (; j + 7 < end; j += 8) {
        float2 c0 = csr[j+0], c1 = csr[j+1], c2 = csr[j+2], c3 = csr[j+3];
        float2 c4 = csr[j+4], c5 = csr[j+5], c6 = csr[j+6], c7 = csr[j+7];
        float2 v0 = h2[__float_as_int(c0.x) * 64 + lane];
        float2 v1 = h2[__float_as_int(c1.x) * 64 + lane];
        float2 v2 = h2[__float_as_int(c2.x) * 64 + lane];
        float2 v3 = h2[__float_as_int(c3.x) * 64 + lane];
        float2 v4 = h2[__float_as_int(c4.x) * 64 + lane];
        float2 v5 = h2[__float_as_int(c5.x) * 64 + lane];
        float2 v6 = h2[__float_as_int(c6.x) * 64 + lane];
        float2 v7 = h2[__float_as_int(c7.x) * 64 + lane];
        ax += c0.y*v0.x + c1.y*v1.x + c2.y*v2.x + c3.y*v3.x
            + c4.y*v4.x + c5.y*v5.x + c6.y*v6.x + c7.y*v7.x;
        ay += c0.y*v0.y + c1.y*v1.y + c2.y*v2.y + c3.y*v3.y
            + c4.y*v4.y + c5.y*v5.y + c6.y*v6.y + c7.y*v7.y;
    }
    for (; j + 3 < end; j += 4) {
        float2 c0 = csr[j+0], c1 = csr[j+1], c2 = csr[j+2], c3 = csr[j+3];
        float2 v0 = h2[__float_as_int(c0.x) * 64 + lane];
        float2 v1 = h2[__float_as_int(c1.x) * 64 + lane];
        float2 v2 = h2[__float_as_int(c2.x) * 64 + lane];
        float2 v3 = h2[__float_as_int(c3.x) * 64 + lane];
        ax += c0.y*v0.x + c1.y*v1.x + c2.y*v2.x + c3.y*v3.x;
        ay += c0.y*v0.y + c1.y*v1.y + c2.y*v2.y + c3.y*v3.y;
    }
    for (; j < end; ++j) {
        float2 c = csr[j];
        float2 v = h2[__float_as_int(c.x) * 64 + lane];
        ax += c.y * v.x;
        ay += c.y * v.y;
    }
    float2 bv = ((const float2*)bias)[lane];
    float2 ov = {fmaxf(ax + bv.x, 0.f), fmaxf(ay + bv.y, 0.f)};
    ((float2*)o)[node * 64 + lane] = ov;
}

// ---------- MFMA bf16x3 GEMM: C[64rows x 128] = sum_h A_h @ W[h*128:...] ----------
// nhalf=1: C = A0@W (+bias). nhalf=2: C = A0@W[0:128] + A1@W[128:256] (+bias).
__global__ __launch_bounds__(256, 2) void k_gemm_mfma(
    const float* __restrict__ A0, const float* __restrict__ A1,
    const float* __restrict__ W, const float* __restrict__ bias,
    float* __restrict__ C, int n, int nhalf)
{
    // A fragments, hi/lo: [kstep 4][mtile 4][lane 64][j 8] bf16
    __shared__ unsigned short Ah[4 * 4 * 64 * 8];   // 16 KB
    __shared__ unsigned short Al[4 * 4 * 64 * 8];   // 16 KB
    int tid = threadIdx.x;
    int l = tid & 63;
    int wv = tid >> 6;               // wave -> cols [wv*32, wv*32+32)
    int brow = blockIdx.x * 64;
    int colbase = wv * 32;
    int lanen = l & 15;
    int kb = (l >> 4) * 8;

    f32x4 acc[4][2];
#pragma unroll
    for (int m = 0; m < 4; ++m)
#pragma unroll
        for (int t = 0; t < 2; ++t) acc[m][t] = (f32x4){0.f, 0.f, 0.f, 0.f};

    for (int h = 0; h < nhalf; ++h) {
        if (h) __syncthreads();      // all reads of LDS done before restage
        const float* A = (h == 0) ? A0 : A1;

        // ---- stage A tile (64x128 fp32 -> hi/lo bf16, fragment order) ----
        const float4* A4 = (const float4*)(A + (size_t)brow * D128);
#pragma unroll
        for (int it = 0; it < 8; ++it) {
            int f = it * 256 + tid;
            int r = f >> 5, k4 = f & 31;           // row, float4-idx (k0 = 4*k4)
            float4 v = make_float4(0.f, 0.f, 0.f, 0.f);
            if (brow + r < n) v = A4[f];
            int lane_ = (r & 15) + 16 * ((k4 >> 1) & 3);          // m + 16*kblk
            int base = ((((k4 >> 3) * 4 + (r >> 4)) * 64 + lane_) << 3) + (k4 & 1) * 4;
            float vv[4] = {v.x, v.y, v.z, v.w};
            ushort4 hh, ll;
            unsigned short* hp = (unsigned short*)&hh;
            unsigned short* lp = (unsigned short*)&ll;
#pragma unroll
            for (int q = 0; q < 4; ++q) {
                unsigned short hb = f2bf_bits(vv[q]);
                hp[q] = hb;
                lp[q] = f2bf_bits(vv[q] - bf2f(hb));
            }
            *(ushort4*)&Ah[base] = hh;
            *(ushort4*)&Al[base] = ll;
        }
        __syncthreads();

        // ---- W fragments into registers (hi/lo) ----
        bf16x8 wh[2][4], wl[2][4];
        const float* Wh = W + (size_t)h * 128 * D128;
#pragma unroll
        for (int t = 0; t < 2; ++t)
#pragma unroll
            for (int s = 0; s < 4; ++s) {
#pragma unroll
                for (int j = 0; j < 8; ++j) {
                    float v = Wh[(size_t)(s * 32 + kb + j) * D128 + colbase + t * 16 + lanen];
                    unsigned short hb = f2bf_bits(v);
                    wh[t][s][j] = (short)hb;
                    wl[t][s][j] = (short)f2bf_bits(v - bf2f(hb));
                }
            }

        // ---- MFMA main loop: hi*hi + lo*hi + hi*lo ----
#pragma unroll
        for (int s = 0; s < 4; ++s) {
#pragma unroll
            for (int m = 0; m < 4; ++m) {
                int fb = ((s * 4 + m) * 64 + l) * 8;
                bf16x8 ah = *(const bf16x8*)&Ah[fb];
                bf16x8 al = *(const bf16x8*)&Al[fb];
#pragma unroll
                for (int t = 0; t < 2; ++t) {
                    acc[m][t] = __builtin_amdgcn_mfma_f32_16x16x32_bf16(ah, wh[t][s], acc[m][t], 0, 0, 0);
                    acc[m][t] = __builtin_amdgcn_mfma_f32_16x16x32_bf16(al, wh[t][s], acc[m][t], 0, 0, 0);
                    acc[m][t] = __builtin_amdgcn_mfma_f32_16x16x32_bf16(ah, wl[t][s], acc[m][t], 0, 0, 0);
                }
            }
        }
    }

    // ---- epilogue: D col=lane&15, row=(lane>>4)*4+reg ----
    float bv[2] = {0.f, 0.f};
    if (bias) { bv[0] = bias[colbase + lanen]; bv[1] = bias[colbase + 16 + lanen]; }
    int rsub = (l >> 4) * 4;
#pragma unroll
    for (int m = 0; m < 4; ++m)
#pragma unroll
        for (int t = 0; t < 2; ++t)
#pragma unroll
            for (int r = 0; r < 4; ++r) {
                int row = brow + m * 16 + rsub + r;
                if (row < n)
                    C[(size_t)row * D128 + colbase + t * 16 + lanen] = acc[m][t][r] + bv[t];
            }
}

extern "C" void kernel_launch(void* const* d_in, const int* in_sizes, int n_in,
                              void* d_out, int out_size, void* d_ws, size_t ws_size,
                              hipStream_t stream) {
    const float* x    = (const float*)d_in[0];
    const int*   ei   = (const int*)d_in[1];
    const float* W1   = (const float*)d_in[2];
    const float* b1   = (const float*)d_in[3];
    const float* W2   = (const float*)d_in[4];
    const float* b2   = (const float*)d_in[5];
    const float* linW = (const float*)d_in[6];
    const float* linb = (const float*)d_in[7];

    int n = in_sizes[0] / D128;
    int E = in_sizes[1] / 2;
    const int* src = ei;
    const int* dst = ei + E;

    float* out = (float*)d_out;
    float* ws  = (float*)d_ws;

    // ws layout (floats): csr[2E] | indeg[n] | dinv[n] | row_ptr[n+1] | bsum[256]
    //                     | cursor[n] | (align) | x1[n*128] | x2[n*128]
    size_t o = 0;
    float2* csr   = (float2*)(ws + o);  o += 2 * (size_t)E;
    int*   indeg  = (int*)(ws + o);     o += n;
    float* dinv   = ws + o;             o += n;
    int*   row_ptr= (int*)(ws + o);     o += n + 1;
    int*   bsum   = (int*)(ws + o);     o += 256;
    int*   cursor = (int*)(ws + o);     o += n;
    o = (o + 3) & ~(size_t)3;
    float* x1     = ws + o;             o += (size_t)n * D128;
    float* x2     = ws + o;
    float* h      = out;  // reuse output buffer as GEMM scratch

    int gn = (n + 255) / 256;
    int gE = (E + 255) / 256;
    int gemmBlocks = (n + 63) / 64;
    int aggBlocks  = (n + 3) / 4;

    // CSR build
    (void)hipMemsetAsync(indeg, 0, (size_t)n * sizeof(int), stream);
    k_count<<<gE, 256, 0, stream>>>(dst, indeg, E);
    k_scan1<<<gn, 256, 0, stream>>>(indeg, row_ptr, bsum, dinv, n);
    k_scan2<<<1, 256, 0, stream>>>(bsum, gn);
    k_scan3<<<gn, 256, 0, stream>>>(row_ptr, bsum, cursor, n, E);
    k_fill<<<gE, 256, 0, stream>>>(src, dst, dinv, cursor, csr, E);

    // layer 1
    k_gemm_mfma<<<gemmBlocks, 256, 0, stream>>>(x, nullptr, W1, nullptr, h, n, 1);
    k_agg_csr<<<aggBlocks, 256, 0, stream>>>(h, row_ptr, csr, dinv, b1, x1, n);

    // layer 2
    k_gemm_mfma<<<gemmBlocks, 256, 0, stream>>>(x1, nullptr, W2, nullptr, h, n, 1);
    k_agg_csr<<<aggBlocks, 256, 0, stream>>>(h, row_ptr, csr, dinv, b2, x2, n);

    // final: out = [x1,x2] @ linW + linb
    k_gemm_mfma<<<gemmBlocks, 256, 0, stream>>>(x1, x2, linW, linb, out, n, 2);
}

// Round 11
// 254.704 us; speedup vs baseline: 12.7560x; 1.1819x over previous
//
#include <hip/hip_runtime.h>

// GCN: x1 = relu(Agg(x@W1)+b1); x2 = relu(Agg(x1@W2)+b2); out = [x1,x2]@linW + linb
// Agg via CSR (counting sort) + per-node wave gather-reduce.
// h (GEMM output feeding Agg) stored as bf16: halves the random-gather traffic
// (FETCH was 188 MB ~ 8 XCDs x full h; no locality exists in a uniform graph).
// GEMMs via MFMA bf16x3 fp32-emulation (hi*hi + lo*hi + hi*lo), proven R10.

#define D128 128

typedef __attribute__((ext_vector_type(8))) short bf16x8;
typedef __attribute__((ext_vector_type(4))) float f32x4;

__device__ __forceinline__ unsigned short f2bf_bits(float v) {
    unsigned int u = __float_as_uint(v);
    unsigned int r = u + 0x7FFFu + ((u >> 16) & 1u);   // RNE
    return (unsigned short)(r >> 16);
}
__device__ __forceinline__ float bf2f(unsigned short h) {
    return __uint_as_float(((unsigned int)h) << 16);
}

// ---------- degree count ----------
__global__ void k_count(const int* __restrict__ dst, int* __restrict__ indeg, int E) {
    int e = blockIdx.x * 256 + threadIdx.x;
    if (e < E) atomicAdd(&indeg[dst[e]], 1);
}

// ---------- scan (exclusive) over indeg -> row_ptr ; fused dinv ----------
__global__ void k_scan1(const int* __restrict__ indeg, int* __restrict__ row_ptr,
                        int* __restrict__ bsum, float* __restrict__ dinv, int n) {
    __shared__ int tmp[256];
    int i = blockIdx.x * 256 + threadIdx.x;
    int v = (i < n) ? indeg[i] : 0;
    if (i < n) dinv[i] = rsqrtf((float)(v + 1));  // +1 self loop
    tmp[threadIdx.x] = v;
    __syncthreads();
    for (int off = 1; off < 256; off <<= 1) {
        int t = (threadIdx.x >= off) ? tmp[threadIdx.x - off] : 0;
        __syncthreads();
        tmp[threadIdx.x] += t;
        __syncthreads();
    }
    if (i < n) row_ptr[i] = tmp[threadIdx.x] - v;
    if (threadIdx.x == 255) bsum[blockIdx.x] = tmp[255];
}

__global__ void k_scan2(int* __restrict__ bsum, int nb) {  // one block, nb<=256
    __shared__ int tmp[256];
    int v = (threadIdx.x < nb) ? bsum[threadIdx.x] : 0;
    tmp[threadIdx.x] = v;
    __syncthreads();
    for (int off = 1; off < 256; off <<= 1) {
        int t = (threadIdx.x >= off) ? tmp[threadIdx.x - off] : 0;
        __syncthreads();
        tmp[threadIdx.x] += t;
        __syncthreads();
    }
    if (threadIdx.x < nb) bsum[threadIdx.x] = tmp[threadIdx.x] - v;
}

__global__ void k_scan3(int* __restrict__ row_ptr, const int* __restrict__ bsum,
                        int* __restrict__ cursor, int n, int E) {
    int i = blockIdx.x * 256 + threadIdx.x;
    if (i < n) {
        int r = row_ptr[i] + bsum[blockIdx.x];
        row_ptr[i] = r;
        cursor[i] = r;
    }
    if (blockIdx.x == 0 && threadIdx.x == 0) row_ptr[n] = E;
}

// ---------- CSR fill: packed (src_bits, norm) ----------
__global__ void k_fill(const int* __restrict__ src, const int* __restrict__ dst,
                       const float* __restrict__ dinv, int* __restrict__ cursor,
                       float2* __restrict__ csr, int E) {
    int e = blockIdx.x * 256 + threadIdx.x;
    if (e >= E) return;
    int s = src[e], d = dst[e];
    int pos = atomicAdd(&cursor[d], 1);
    csr[pos] = make_float2(__int_as_float(s), dinv[s] * dinv[d]);
}

// ---------- fused aggregate + bias + relu ; h is packed bf16x2 ----------
// 1 wave per node, one uint (2 bf16 ch) per lane; 8 gathers in flight.
__global__ __launch_bounds__(256) void k_agg_csr(
    const unsigned int* __restrict__ h, const int* __restrict__ row_ptr,
    const float2* __restrict__ csr, const float* __restrict__ dinv,
    const float* __restrict__ bias, float* __restrict__ o, int n)
{
    int node = blockIdx.x * 4 + (threadIdx.x >> 6);
    int lane = threadIdx.x & 63;
    if (node >= n) return;
    float dv = dinv[node];
    unsigned int su = h[node * 64 + lane];
    float ax = dv * dv * __uint_as_float(su << 16);
    float ay = dv * dv * __uint_as_float(su & 0xFFFF0000u);
    int j = row_ptr[node], end = row_ptr[node + 1];
    for (; j + 7 < end; j += 8) {
        float2 c0 = csr[j+0], c1 = csr[j+1], c2 = csr[j+2], c3 = csr[j+3];
        float2 c4 = csr[j+4], c5 = csr[j+5], c6 = csr[j+6], c7 = csr[j+7];
        unsigned int u0 = h[__float_as_int(c0.x) * 64 + lane];
        unsigned int u1 = h[__float_as_int(c1.x) * 64 + lane];
        unsigned int u2 = h[__float_as_int(c2.x) * 64 + lane];
        unsigned int u3 = h[__float_as_int(c3.x) * 64 + lane];
        unsigned int u4 = h[__float_as_int(c4.x) * 64 + lane];
        unsigned int u5 = h[__float_as_int(c5.x) * 64 + lane];
        unsigned int u6 = h[__float_as_int(c6.x) * 64 + lane];
        unsigned int u7 = h[__float_as_int(c7.x) * 64 + lane];
        ax += c0.y*__uint_as_float(u0 << 16) + c1.y*__uint_as_float(u1 << 16)
            + c2.y*__uint_as_float(u2 << 16) + c3.y*__uint_as_float(u3 << 16)
            + c4.y*__uint_as_float(u4 << 16) + c5.y*__uint_as_float(u5 << 16)
            + c6.y*__uint_as_float(u6 << 16) + c7.y*__uint_as_float(u7 << 16);
        ay += c0.y*__uint_as_float(u0 & 0xFFFF0000u) + c1.y*__uint_as_float(u1 & 0xFFFF0000u)
            + c2.y*__uint_as_float(u2 & 0xFFFF0000u) + c3.y*__uint_as_float(u3 & 0xFFFF0000u)
            + c4.y*__uint_as_float(u4 & 0xFFFF0000u) + c5.y*__uint_as_float(u5 & 0xFFFF0000u)
            + c6.y*__uint_as_float(u6 & 0xFFFF0000u) + c7.y*__uint_as_float(u7 & 0xFFFF0000u);
    }
    for (; j + 3 < end; j += 4) {
        float2 c0 = csr[j+0], c1 = csr[j+1], c2 = csr[j+2], c3 = csr[j+3];
        unsigned int u0 = h[__float_as_int(c0.x) * 64 + lane];
        unsigned int u1 = h[__float_as_int(c1.x) * 64 + lane];
        unsigned int u2 = h[__float_as_int(c2.x) * 64 + lane];
        unsigned int u3 = h[__float_as_int(c3.x) * 64 + lane];
        ax += c0.y*__uint_as_float(u0 << 16) + c1.y*__uint_as_float(u1 << 16)
            + c2.y*__uint_as_float(u2 << 16) + c3.y*__uint_as_float(u3 << 16);
        ay += c0.y*__uint_as_float(u0 & 0xFFFF0000u) + c1.y*__uint_as_float(u1 & 0xFFFF0000u)
            + c2.y*__uint_as_float(u2 & 0xFFFF0000u) + c3.y*__uint_as_float(u3 & 0xFFFF0000u);
    }
    for (; j < end; ++j) {
        float2 c = csr[j];
        unsigned int u = h[__float_as_int(c.x) * 64 + lane];
        ax += c.y * __uint_as_float(u << 16);
        ay += c.y * __uint_as_float(u & 0xFFFF0000u);
    }
    float2 bv = ((const float2*)bias)[lane];
    float2 ov = {fmaxf(ax + bv.x, 0.f), fmaxf(ay + bv.y, 0.f)};
    ((float2*)o)[node * 64 + lane] = ov;
}

// ---------- MFMA bf16x3 GEMM: C[64rows x 128] = sum_h A_h @ W[h*128:...] ----------
// out_bf: 1 -> write packed bf16 (no bias), 0 -> write fp32 (+bias).
__global__ __launch_bounds__(256, 2) void k_gemm_mfma(
    const float* __restrict__ A0, const float* __restrict__ A1,
    const float* __restrict__ W, const float* __restrict__ bias,
    float* __restrict__ C, int n, int nhalf, int out_bf)
{
    // A fragments, hi/lo: [kstep 4][mtile 4][lane 64][j 8] bf16
    __shared__ unsigned short Ah[4 * 4 * 64 * 8];   // 16 KB
    __shared__ unsigned short Al[4 * 4 * 64 * 8];   // 16 KB
    int tid = threadIdx.x;
    int l = tid & 63;
    int wv = tid >> 6;               // wave -> cols [wv*32, wv*32+32)
    int brow = blockIdx.x * 64;
    int colbase = wv * 32;
    int lanen = l & 15;
    int kb = (l >> 4) * 8;

    f32x4 acc[4][2];
#pragma unroll
    for (int m = 0; m < 4; ++m)
#pragma unroll
        for (int t = 0; t < 2; ++t) acc[m][t] = (f32x4){0.f, 0.f, 0.f, 0.f};

    for (int h = 0; h < nhalf; ++h) {
        if (h) __syncthreads();      // all reads of LDS done before restage
        const float* A = (h == 0) ? A0 : A1;

        // ---- stage A tile (64x128 fp32 -> hi/lo bf16, fragment order) ----
        const float4* A4 = (const float4*)(A + (size_t)brow * D128);
#pragma unroll
        for (int it = 0; it < 8; ++it) {
            int f = it * 256 + tid;
            int r = f >> 5, k4 = f & 31;           // row, float4-idx (k0 = 4*k4)
            float4 v = make_float4(0.f, 0.f, 0.f, 0.f);
            if (brow + r < n) v = A4[f];
            int lane_ = (r & 15) + 16 * ((k4 >> 1) & 3);          // m + 16*kblk
            int base = ((((k4 >> 3) * 4 + (r >> 4)) * 64 + lane_) << 3) + (k4 & 1) * 4;
            float vv[4] = {v.x, v.y, v.z, v.w};
            ushort4 hh, ll;
            unsigned short* hp = (unsigned short*)&hh;
            unsigned short* lp = (unsigned short*)&ll;
#pragma unroll
            for (int q = 0; q < 4; ++q) {
                unsigned short hb = f2bf_bits(vv[q]);
                hp[q] = hb;
                lp[q] = f2bf_bits(vv[q] - bf2f(hb));
            }
            *(ushort4*)&Ah[base] = hh;
            *(ushort4*)&Al[base] = ll;
        }
        __syncthreads();

        // ---- W fragments into registers (hi/lo) ----
        bf16x8 wh[2][4], wl[2][4];
        const float* Wh = W + (size_t)h * 128 * D128;
#pragma unroll
        for (int t = 0; t < 2; ++t)
#pragma unroll
            for (int s = 0; s < 4; ++s) {
#pragma unroll
                for (int j = 0; j < 8; ++j) {
                    float v = Wh[(size_t)(s * 32 + kb + j) * D128 + colbase + t * 16 + lanen];
                    unsigned short hb = f2bf_bits(v);
                    wh[t][s][j] = (short)hb;
                    wl[t][s][j] = (short)f2bf_bits(v - bf2f(hb));
                }
            }

        // ---- MFMA main loop: hi*hi + lo*hi + hi*lo ----
#pragma unroll
        for (int s = 0; s < 4; ++s) {
#pragma unroll
            for (int m = 0; m < 4; ++m) {
                int fb = ((s * 4 + m) * 64 + l) * 8;
                bf16x8 ah = *(const bf16x8*)&Ah[fb];
                bf16x8 al = *(const bf16x8*)&Al[fb];
#pragma unroll
                for (int t = 0; t < 2; ++t) {
                    acc[m][t] = __builtin_amdgcn_mfma_f32_16x16x32_bf16(ah, wh[t][s], acc[m][t], 0, 0, 0);
                    acc[m][t] = __builtin_amdgcn_mfma_f32_16x16x32_bf16(al, wh[t][s], acc[m][t], 0, 0, 0);
                    acc[m][t] = __builtin_amdgcn_mfma_f32_16x16x32_bf16(ah, wl[t][s], acc[m][t], 0, 0, 0);
                }
            }
        }
    }

    // ---- epilogue: D col=lane&15, row=(lane>>4)*4+reg ----
    float bv[2] = {0.f, 0.f};
    if (bias) { bv[0] = bias[colbase + lanen]; bv[1] = bias[colbase + 16 + lanen]; }
    int rsub = (l >> 4) * 4;
    if (out_bf) {
        unsigned short* Cb = (unsigned short*)C;
#pragma unroll
        for (int m = 0; m < 4; ++m)
#pragma unroll
            for (int t = 0; t < 2; ++t)
#pragma unroll
                for (int r = 0; r < 4; ++r) {
                    int row = brow + m * 16 + rsub + r;
                    if (row < n)
                        Cb[(size_t)row * D128 + colbase + t * 16 + lanen] = f2bf_bits(acc[m][t][r]);
                }
    } else {
#pragma unroll
        for (int m = 0; m < 4; ++m)
#pragma unroll
            for (int t = 0; t < 2; ++t)
#pragma unroll
                for (int r = 0; r < 4; ++r) {
                    int row = brow + m * 16 + rsub + r;
                    if (row < n)
                        C[(size_t)row * D128 + colbase + t * 16 + lanen] = acc[m][t][r] + bv[t];
                }
    }
}

extern "C" void kernel_launch(void* const* d_in, const int* in_sizes, int n_in,
                              void* d_out, int out_size, void* d_ws, size_t ws_size,
                              hipStream_t stream) {
    const float* x    = (const float*)d_in[0];
    const int*   ei   = (const int*)d_in[1];
    const float* W1   = (const float*)d_in[2];
    const float* b1   = (const float*)d_in[3];
    const float* W2   = (const float*)d_in[4];
    const float* b2   = (const float*)d_in[5];
    const float* linW = (const float*)d_in[6];
    const float* linb = (const float*)d_in[7];

    int n = in_sizes[0] / D128;
    int E = in_sizes[1] / 2;
    const int* src = ei;
    const int* dst = ei + E;

    float* out = (float*)d_out;
    float* ws  = (float*)d_ws;

    // ws layout (floats): csr[2E] | indeg[n] | dinv[n] | row_ptr[n+1] | bsum[256]
    //                     | cursor[n] | (align) | x1[n*128] | x2[n*128]
    size_t o = 0;
    float2* csr   = (float2*)(ws + o);  o += 2 * (size_t)E;
    int*   indeg  = (int*)(ws + o);     o += n;
    float* dinv   = ws + o;             o += n;
    int*   row_ptr= (int*)(ws + o);     o += n + 1;
    int*   bsum   = (int*)(ws + o);     o += 256;
    int*   cursor = (int*)(ws + o);     o += n;
    o = (o + 3) & ~(size_t)3;
    float* x1     = ws + o;             o += (size_t)n * D128;
    float* x2     = ws + o;
    float* h      = out;  // bf16-packed GEMM output lives in the out buffer

    int gn = (n + 255) / 256;
    int gE = (E + 255) / 256;
    int gemmBlocks = (n + 63) / 64;
    int aggBlocks  = (n + 3) / 4;

    // CSR build
    (void)hipMemsetAsync(indeg, 0, (size_t)n * sizeof(int), stream);
    k_count<<<gE, 256, 0, stream>>>(dst, indeg, E);
    k_scan1<<<gn, 256, 0, stream>>>(indeg, row_ptr, bsum, dinv, n);
    k_scan2<<<1, 256, 0, stream>>>(bsum, gn);
    k_scan3<<<gn, 256, 0, stream>>>(row_ptr, bsum, cursor, n, E);
    k_fill<<<gE, 256, 0, stream>>>(src, dst, dinv, cursor, csr, E);

    // layer 1
    k_gemm_mfma<<<gemmBlocks, 256, 0, stream>>>(x, nullptr, W1, nullptr, h, n, 1, 1);
    k_agg_csr<<<aggBlocks, 256, 0, stream>>>((const unsigned int*)h, row_ptr, csr, dinv, b1, x1, n);

    // layer 2
    k_gemm_mfma<<<gemmBlocks, 256, 0, stream>>>(x1, nullptr, W2, nullptr, h, n, 1, 1);
    k_agg_csr<<<aggBlocks, 256, 0, stream>>>((const unsigned int*)h, row_ptr, csr, dinv, b2, x2, n);

    // final: out = [x1,x2] @ linW + linb
    k_gemm_mfma<<<gemmBlocks, 256, 0, stream>>>(x1, x2, linW, linb, out, n, 2, 0);
}

// Round 12
// 228.478 us; speedup vs baseline: 14.2202x; 1.1148x over previous
//
#include <hip/hip_runtime.h>

// GCN: x1 = relu(Agg(x@W1)+b1); x2 = relu(Agg(x1@W2)+b2); out = [x1,x2]@linW + linb
// Agg via CSR (counting sort) + per-node wave gather-reduce; h stored bf16.
// GEMMs via MFMA bf16x3 fp32-emulation (hi*hi + lo*hi + hi*lo), R10-verified.
// R12: (a) fuse latency-bound k_fill (50us, VALU 0.5%) with compute-bound gemm1
// in one heterogeneous dispatch; (b) k_gemm_dual: x1@W2 and x1@linW_top share
// one A-tile staging; (c) gemm3b accumulates x2@linW_bot + partial + bias.

#define D128 128

typedef __attribute__((ext_vector_type(8))) short bf16x8;
typedef __attribute__((ext_vector_type(4))) float f32x4;

__device__ __forceinline__ unsigned short f2bf_bits(float v) {
    unsigned int u = __float_as_uint(v);
    unsigned int r = u + 0x7FFFu + ((u >> 16) & 1u);   // RNE
    return (unsigned short)(r >> 16);
}
__device__ __forceinline__ float bf2f(unsigned short h) {
    return __uint_as_float(((unsigned int)h) << 16);
}
__device__ __forceinline__ void mfma3(f32x4& acc, bf16x8 ah, bf16x8 al,
                                      bf16x8 wh, bf16x8 wl) {
    acc = __builtin_amdgcn_mfma_f32_16x16x32_bf16(ah, wh, acc, 0, 0, 0);
    acc = __builtin_amdgcn_mfma_f32_16x16x32_bf16(al, wh, acc, 0, 0, 0);
    acc = __builtin_amdgcn_mfma_f32_16x16x32_bf16(ah, wl, acc, 0, 0, 0);
}

// ---------- degree count ----------
__global__ void k_count(const int* __restrict__ dst, int* __restrict__ indeg, int E) {
    int e = blockIdx.x * 256 + threadIdx.x;
    if (e < E) atomicAdd(&indeg[dst[e]], 1);
}

// ---------- scan (exclusive) over indeg -> row_ptr ; fused dinv ----------
__global__ void k_scan1(const int* __restrict__ indeg, int* __restrict__ row_ptr,
                        int* __restrict__ bsum, float* __restrict__ dinv, int n) {
    __shared__ int tmp[256];
    int i = blockIdx.x * 256 + threadIdx.x;
    int v = (i < n) ? indeg[i] : 0;
    if (i < n) dinv[i] = rsqrtf((float)(v + 1));  // +1 self loop
    tmp[threadIdx.x] = v;
    __syncthreads();
    for (int off = 1; off < 256; off <<= 1) {
        int t = (threadIdx.x >= off) ? tmp[threadIdx.x - off] : 0;
        __syncthreads();
        tmp[threadIdx.x] += t;
        __syncthreads();
    }
    if (i < n) row_ptr[i] = tmp[threadIdx.x] - v;
    if (threadIdx.x == 255) bsum[blockIdx.x] = tmp[255];
}

__global__ void k_scan2(int* __restrict__ bsum, int nb) {  // one block, nb<=256
    __shared__ int tmp[256];
    int v = (threadIdx.x < nb) ? bsum[threadIdx.x] : 0;
    tmp[threadIdx.x] = v;
    __syncthreads();
    for (int off = 1; off < 256; off <<= 1) {
        int t = (threadIdx.x >= off) ? tmp[threadIdx.x - off] : 0;
        __syncthreads();
        tmp[threadIdx.x] += t;
        __syncthreads();
    }
    if (threadIdx.x < nb) bsum[threadIdx.x] = tmp[threadIdx.x] - v;
}

__global__ void k_scan3(int* __restrict__ row_ptr, const int* __restrict__ bsum,
                        int* __restrict__ cursor, int n, int E) {
    int i = blockIdx.x * 256 + threadIdx.x;
    if (i < n) {
        int r = row_ptr[i] + bsum[blockIdx.x];
        row_ptr[i] = r;
        cursor[i] = r;
    }
    if (blockIdx.x == 0 && threadIdx.x == 0) row_ptr[n] = E;
}

// ---------- fused aggregate + bias + relu ; h is packed bf16x2 ----------
__global__ __launch_bounds__(256) void k_agg_csr(
    const unsigned int* __restrict__ h, const int* __restrict__ row_ptr,
    const float2* __restrict__ csr, const float* __restrict__ dinv,
    const float* __restrict__ bias, float* __restrict__ o, int n)
{
    int node = blockIdx.x * 4 + (threadIdx.x >> 6);
    int lane = threadIdx.x & 63;
    if (node >= n) return;
    float dv = dinv[node];
    unsigned int su = h[node * 64 + lane];
    float ax = dv * dv * __uint_as_float(su << 16);
    float ay = dv * dv * __uint_as_float(su & 0xFFFF0000u);
    int j = row_ptr[node], end = row_ptr[node + 1];
    for (; j + 7 < end; j += 8) {
        float2 c0 = csr[j+0], c1 = csr[j+1], c2 = csr[j+2], c3 = csr[j+3];
        float2 c4 = csr[j+4], c5 = csr[j+5], c6 = csr[j+6], c7 = csr[j+7];
        unsigned int u0 = h[__float_as_int(c0.x) * 64 + lane];
        unsigned int u1 = h[__float_as_int(c1.x) * 64 + lane];
        unsigned int u2 = h[__float_as_int(c2.x) * 64 + lane];
        unsigned int u3 = h[__float_as_int(c3.x) * 64 + lane];
        unsigned int u4 = h[__float_as_int(c4.x) * 64 + lane];
        unsigned int u5 = h[__float_as_int(c5.x) * 64 + lane];
        unsigned int u6 = h[__float_as_int(c6.x) * 64 + lane];
        unsigned int u7 = h[__float_as_int(c7.x) * 64 + lane];
        ax += c0.y*__uint_as_float(u0 << 16) + c1.y*__uint_as_float(u1 << 16)
            + c2.y*__uint_as_float(u2 << 16) + c3.y*__uint_as_float(u3 << 16)
            + c4.y*__uint_as_float(u4 << 16) + c5.y*__uint_as_float(u5 << 16)
            + c6.y*__uint_as_float(u6 << 16) + c7.y*__uint_as_float(u7 << 16);
        ay += c0.y*__uint_as_float(u0 & 0xFFFF0000u) + c1.y*__uint_as_float(u1 & 0xFFFF0000u)
            + c2.y*__uint_as_float(u2 & 0xFFFF0000u) + c3.y*__uint_as_float(u3 & 0xFFFF0000u)
            + c4.y*__uint_as_float(u4 & 0xFFFF0000u) + c5.y*__uint_as_float(u5 & 0xFFFF0000u)
            + c6.y*__uint_as_float(u6 & 0xFFFF0000u) + c7.y*__uint_as_float(u7 & 0xFFFF0000u);
    }
    for (; j + 3 < end; j += 4) {
        float2 c0 = csr[j+0], c1 = csr[j+1], c2 = csr[j+2], c3 = csr[j+3];
        unsigned int u0 = h[__float_as_int(c0.x) * 64 + lane];
        unsigned int u1 = h[__float_as_int(c1.x) * 64 + lane];
        unsigned int u2 = h[__float_as_int(c2.x) * 64 + lane];
        unsigned int u3 = h[__float_as_int(c3.x) * 64 + lane];
        ax += c0.y*__uint_as_float(u0 << 16) + c1.y*__uint_as_float(u1 << 16)
            + c2.y*__uint_as_float(u2 << 16) + c3.y*__uint_as_float(u3 << 16);
        ay += c0.y*__uint_as_float(u0 & 0xFFFF0000u) + c1.y*__uint_as_float(u1 & 0xFFFF0000u)
            + c2.y*__uint_as_float(u2 & 0xFFFF0000u) + c3.y*__uint_as_float(u3 & 0xFFFF0000u);
    }
    for (; j < end; ++j) {
        float2 c = csr[j];
        unsigned int u = h[__float_as_int(c.x) * 64 + lane];
        ax += c.y * __uint_as_float(u << 16);
        ay += c.y * __uint_as_float(u & 0xFFFF0000u);
    }
    float2 bv = ((const float2*)bias)[lane];
    float2 ov = {fmaxf(ax + bv.x, 0.f), fmaxf(ay + bv.y, 0.f)};
    ((float2*)o)[node * 64 + lane] = ov;
}

// ---------- MFMA GEMM building blocks (R10-verified layouts) ----------
// A-frag LDS order: [s 4][m 4][lane 64][j 8]; lane_=(r&15)+16*((k4>>1)&3).
__device__ __forceinline__ void stage_A_tile(
    const float* __restrict__ A, int brow, int n, int tid,
    unsigned short* __restrict__ Ah, unsigned short* __restrict__ Al)
{
    const float4* A4 = (const float4*)(A + (size_t)brow * D128);
#pragma unroll
    for (int it = 0; it < 8; ++it) {
        int f = it * 256 + tid;
        int r = f >> 5, k4 = f & 31;
        float4 v = make_float4(0.f, 0.f, 0.f, 0.f);
        if (brow + r < n) v = A4[f];
        int lane_ = (r & 15) + 16 * ((k4 >> 1) & 3);
        int base = ((((k4 >> 3) * 4 + (r >> 4)) * 64 + lane_) << 3) + (k4 & 1) * 4;
        float vv[4] = {v.x, v.y, v.z, v.w};
        ushort4 hh, ll;
        unsigned short* hp = (unsigned short*)&hh;
        unsigned short* lp = (unsigned short*)&ll;
#pragma unroll
        for (int q = 0; q < 4; ++q) {
            unsigned short hb = f2bf_bits(vv[q]);
            hp[q] = hb;
            lp[q] = f2bf_bits(vv[q] - bf2f(hb));
        }
        *(ushort4*)&Ah[base] = hh;
        *(ushort4*)&Al[base] = ll;
    }
}

__device__ __forceinline__ void load_W_s(
    const float* __restrict__ W, int s, int colbase, int lanen, int kb,
    bf16x8 wh[2], bf16x8 wl[2])
{
#pragma unroll
    for (int t = 0; t < 2; ++t)
#pragma unroll
        for (int j = 0; j < 8; ++j) {
            float v = W[(size_t)(s * 32 + kb + j) * D128 + colbase + t * 16 + lanen];
            unsigned short hb = f2bf_bits(v);
            wh[t][j] = (short)hb;
            wl[t][j] = (short)f2bf_bits(v - bf2f(hb));
        }
}

__device__ __forceinline__ void epilogue(
    f32x4 acc[4][2], float* __restrict__ C, const float* __restrict__ bias,
    int brow, int n, int colbase, int lanen, int l, int out_bf, int addC)
{
    float bv[2] = {0.f, 0.f};
    if (bias) { bv[0] = bias[colbase + lanen]; bv[1] = bias[colbase + 16 + lanen]; }
    int rsub = (l >> 4) * 4;
    if (out_bf) {
        unsigned short* Cb = (unsigned short*)C;
#pragma unroll
        for (int m = 0; m < 4; ++m)
#pragma unroll
            for (int t = 0; t < 2; ++t)
#pragma unroll
                for (int r = 0; r < 4; ++r) {
                    int row = brow + m * 16 + rsub + r;
                    if (row < n)
                        Cb[(size_t)row * D128 + colbase + t * 16 + lanen] = f2bf_bits(acc[m][t][r]);
                }
    } else {
#pragma unroll
        for (int m = 0; m < 4; ++m)
#pragma unroll
            for (int t = 0; t < 2; ++t)
#pragma unroll
                for (int r = 0; r < 4; ++r) {
                    int row = brow + m * 16 + rsub + r;
                    if (row < n) {
                        size_t idx = (size_t)row * D128 + colbase + t * 16 + lanen;
                        float v = acc[m][t][r] + bv[t];
                        if (addC) v += C[idx];
                        C[idx] = v;
                    }
                }
    }
}

// single-W-source gemm core (optionally accumulating into C)
__device__ __forceinline__ void gemm_core(
    const float* __restrict__ A, const float* __restrict__ W,
    const float* __restrict__ bias, float* __restrict__ C,
    int n, int out_bf, int addC, int bid, int tid,
    unsigned short* __restrict__ Ah, unsigned short* __restrict__ Al)
{
    int l = tid & 63;
    int wv = tid >> 6;
    int brow = bid * 64;
    int colbase = wv * 32;
    int lanen = l & 15;
    int kb = (l >> 4) * 8;

    f32x4 acc[4][2];
#pragma unroll
    for (int m = 0; m < 4; ++m)
#pragma unroll
        for (int t = 0; t < 2; ++t) acc[m][t] = (f32x4){0.f, 0.f, 0.f, 0.f};

    stage_A_tile(A, brow, n, tid, Ah, Al);
    __syncthreads();

#pragma unroll
    for (int s = 0; s < 4; ++s) {
        bf16x8 wh[2], wl[2];
        load_W_s(W, s, colbase, lanen, kb, wh, wl);
#pragma unroll
        for (int m = 0; m < 4; ++m) {
            int fb = ((s * 4 + m) * 64 + l) * 8;
            bf16x8 ah = *(const bf16x8*)&Ah[fb];
            bf16x8 al = *(const bf16x8*)&Al[fb];
#pragma unroll
            for (int t = 0; t < 2; ++t) mfma3(acc[m][t], ah, al, wh[t], wl[t]);
        }
    }
    epilogue(acc, C, bias, brow, n, colbase, lanen, l, out_bf, addC);
}

// ---------- fused: gemm1 (blocks < gemmBlocks) + CSR fill (rest) ----------
__global__ __launch_bounds__(256, 2) void k_gemm1_fill(
    const float* __restrict__ x, const float* __restrict__ W1,
    float* __restrict__ h, int n,
    const int* __restrict__ src, const int* __restrict__ dst,
    const float* __restrict__ dinv, int* __restrict__ cursor,
    float2* __restrict__ csr, int E, int gemmBlocks)
{
    __shared__ unsigned short Ah[4 * 4 * 64 * 8];
    __shared__ unsigned short Al[4 * 4 * 64 * 8];
    if (blockIdx.x < gemmBlocks) {
        gemm_core(x, W1, nullptr, h, n, 1, 0, blockIdx.x, threadIdx.x, Ah, Al);
    } else {
        int e = (blockIdx.x - gemmBlocks) * 256 + threadIdx.x;
        if (e >= E) return;
        int s = src[e], d = dst[e];
        int pos = atomicAdd(&cursor[d], 1);
        csr[pos] = make_float2(__int_as_float(s), dinv[s] * dinv[d]);
    }
}

// ---------- standalone single-source gemm (gemm3b) ----------
__global__ __launch_bounds__(256, 2) void k_gemm_mfma(
    const float* __restrict__ A, const float* __restrict__ W,
    const float* __restrict__ bias, float* __restrict__ C,
    int n, int out_bf, int addC)
{
    __shared__ unsigned short Ah[4 * 4 * 64 * 8];
    __shared__ unsigned short Al[4 * 4 * 64 * 8];
    gemm_core(A, W, bias, C, n, out_bf, addC, blockIdx.x, threadIdx.x, Ah, Al);
}

// ---------- dual: h2 = bf16(x1@W2), p = x1@linW_top (one A staging) ----------
__global__ __launch_bounds__(256, 2) void k_gemm_dual(
    const float* __restrict__ A, const float* __restrict__ W2,
    const float* __restrict__ Wtop, float* __restrict__ hOut,
    float* __restrict__ pOut, int n)
{
    __shared__ unsigned short Ah[4 * 4 * 64 * 8];
    __shared__ unsigned short Al[4 * 4 * 64 * 8];
    int tid = threadIdx.x;
    int l = tid & 63;
    int wv = tid >> 6;
    int brow = blockIdx.x * 64;
    int colbase = wv * 32;
    int lanen = l & 15;
    int kb = (l >> 4) * 8;

    f32x4 accA[4][2], accB[4][2];
#pragma unroll
    for (int m = 0; m < 4; ++m)
#pragma unroll
        for (int t = 0; t < 2; ++t) {
            accA[m][t] = (f32x4){0.f, 0.f, 0.f, 0.f};
            accB[m][t] = (f32x4){0.f, 0.f, 0.f, 0.f};
        }

    stage_A_tile(A, brow, n, tid, Ah, Al);
    __syncthreads();

#pragma unroll
    for (int s = 0; s < 4; ++s) {
        bf16x8 whA[2], wlA[2], whB[2], wlB[2];
        load_W_s(W2, s, colbase, lanen, kb, whA, wlA);
        load_W_s(Wtop, s, colbase, lanen, kb, whB, wlB);
#pragma unroll
        for (int m = 0; m < 4; ++m) {
            int fb = ((s * 4 + m) * 64 + l) * 8;
            bf16x8 ah = *(const bf16x8*)&Ah[fb];
            bf16x8 al = *(const bf16x8*)&Al[fb];
#pragma unroll
            for (int t = 0; t < 2; ++t) {
                mfma3(accA[m][t], ah, al, whA[t], wlA[t]);
                mfma3(accB[m][t], ah, al, whB[t], wlB[t]);
            }
        }
    }
    epilogue(accA, hOut, nullptr, brow, n, colbase, lanen, l, 1, 0);
    epilogue(accB, pOut, nullptr, brow, n, colbase, lanen, l, 0, 0);
}

extern "C" void kernel_launch(void* const* d_in, const int* in_sizes, int n_in,
                              void* d_out, int out_size, void* d_ws, size_t ws_size,
                              hipStream_t stream) {
    const float* x    = (const float*)d_in[0];
    const int*   ei   = (const int*)d_in[1];
    const float* W1   = (const float*)d_in[2];
    const float* b1   = (const float*)d_in[3];
    const float* W2   = (const float*)d_in[4];
    const float* b2   = (const float*)d_in[5];
    const float* linW = (const float*)d_in[6];
    const float* linb = (const float*)d_in[7];

    int n = in_sizes[0] / D128;
    int E = in_sizes[1] / 2;
    const int* src = ei;
    const int* dst = ei + E;

    float* out = (float*)d_out;
    float* ws  = (float*)d_ws;

    // ws (floats): csr[2E] | indeg[n] | dinv[n] | row_ptr[n+1] | bsum[256]
    //              | cursor[n] | align | x1[n*128] | x2[n*128] | h[n*64 uints]
    size_t o = 0;
    float2* csr   = (float2*)(ws + o);  o += 2 * (size_t)E;
    int*   indeg  = (int*)(ws + o);     o += n;
    float* dinv   = ws + o;             o += n;
    int*   row_ptr= (int*)(ws + o);     o += n + 1;
    int*   bsum   = (int*)(ws + o);     o += 256;
    int*   cursor = (int*)(ws + o);     o += n;
    o = (o + 3) & ~(size_t)3;
    float* x1     = ws + o;             o += (size_t)n * D128;
    float* x2     = ws + o;             o += (size_t)n * D128;
    float* h      = ws + o;             // bf16-packed, n*64 uints

    int gn = (n + 255) / 256;
    int gE = (E + 255) / 256;
    int gemmBlocks = (n + 63) / 64;
    int aggBlocks  = (n + 3) / 4;

    // CSR prep
    (void)hipMemsetAsync(indeg, 0, (size_t)n * sizeof(int), stream);
    k_count<<<gE, 256, 0, stream>>>(dst, indeg, E);
    k_scan1<<<gn, 256, 0, stream>>>(indeg, row_ptr, bsum, dinv, n);
    k_scan2<<<1, 256, 0, stream>>>(bsum, gn);
    k_scan3<<<gn, 256, 0, stream>>>(row_ptr, bsum, cursor, n, E);

    // gemm1 (h = bf16(x@W1)) fused with CSR fill
    k_gemm1_fill<<<gemmBlocks + gE, 256, 0, stream>>>(
        x, W1, h, n, src, dst, dinv, cursor, csr, E, gemmBlocks);

    // layer 1 aggregate
    k_agg_csr<<<aggBlocks, 256, 0, stream>>>((const unsigned int*)h, row_ptr, csr, dinv, b1, x1, n);

    // layer 2 gemm + first half of final linear (shared A staging)
    k_gemm_dual<<<gemmBlocks, 256, 0, stream>>>(x1, W2, linW, h, out, n);

    // layer 2 aggregate
    k_agg_csr<<<aggBlocks, 256, 0, stream>>>((const unsigned int*)h, row_ptr, csr, dinv, b2, x2, n);

    // final: out += x2 @ linW[128:256] + linb
    k_gemm_mfma<<<gemmBlocks, 256, 0, stream>>>(x2, linW + 128 * D128, linb, out, n, 0, 1);
}